// Round 5
// baseline (387.654 us; speedup 1.0000x reference)
//
#include <hip/hip_runtime.h>
#include <stdint.h>

#define N_NODES 50000
#define DD 256
#define SS 25

typedef unsigned short u16;
typedef __attribute__((ext_vector_type(8))) __bf16 bf16x8;
typedef __attribute__((ext_vector_type(4))) float f32x4;

__device__ __forceinline__ u16 f2bf(float f) {  // round-to-nearest-even
    union { float f; uint32_t i; } c;
    c.f = f;
    uint32_t r = c.i + 0x7fffu + ((c.i >> 16) & 1u);
    return (u16)(r >> 16);
}

// packed max of 2 non-negative bf16 (bit patterns are monotone, sign bit 0 -> signed i16 max works)
__device__ __forceinline__ uint4 pkmax4(uint4 a, uint4 b) {
    uint4 d;
    asm("v_pk_max_i16 %0, %1, %2" : "=v"(d.x) : "v"(a.x), "v"(b.x));
    asm("v_pk_max_i16 %0, %1, %2" : "=v"(d.y) : "v"(a.y), "v"(b.y));
    asm("v_pk_max_i16 %0, %1, %2" : "=v"(d.z) : "v"(a.z), "v"(b.z));
    asm("v_pk_max_i16 %0, %1, %2" : "=v"(d.w) : "v"(a.w), "v"(b.w));
    return d;
}

// ---- f32 -> bf16 elementwise (exact: grid*block*4 == n) ----
__global__ __launch_bounds__(256) void cvt_f32_bf16_k(const float4* __restrict__ in,
                                                      u16* __restrict__ out) {
    int i = blockIdx.x * 256 + threadIdx.x;
    float4 v = in[i];
    uint2 o;
    o.x = (uint32_t)f2bf(v.x) | ((uint32_t)f2bf(v.y) << 16);
    o.y = (uint32_t)f2bf(v.z) | ((uint32_t)f2bf(v.w) << 16);
    *reinterpret_cast<uint2*>(out + (size_t)i * 4) = o;
}

// ---- weight f32 [K][256] -> bf16 MFMA B-fragment layout ----
__global__ __launch_bounds__(256) void cvt_w_k(const float* __restrict__ W,
                                               u16* __restrict__ out, int KT) {
    int t = blockIdx.x * 256 + threadIdx.x;
    if (t >= KT * 16 * 64) return;
    int lane = t & 63;
    int ct = (t >> 6) & 15;
    int kt = t >> 10;
    int k0 = kt * 32 + (lane >> 4) * 8;
    int col = ct * 16 + (lane & 15);
    u16 r[8];
#pragma unroll
    for (int e = 0; e < 8; e++) r[e] = f2bf(W[(size_t)(k0 + e) * DD + col]);
    uint4 v;
    v.x = (uint32_t)r[0] | ((uint32_t)r[1] << 16);
    v.y = (uint32_t)r[2] | ((uint32_t)r[3] << 16);
    v.z = (uint32_t)r[4] | ((uint32_t)r[5] << 16);
    v.w = (uint32_t)r[6] | ((uint32_t)r[7] << 16);
    *reinterpret_cast<uint4*>(out + (size_t)t * 8) = v;
}

// ---- GEMM1 (LDS-free, barrier-free): out[M,256] = relu(A @ Wp + b), bf16 ----
// Block = 64 rows, 8 waves; wave w owns cols [w*32, w*32+32). K = 256.
__global__ __launch_bounds__(512) void gemm1_k(const u16* __restrict__ A,
                                               const u16* __restrict__ Bf,
                                               const float* __restrict__ bias,
                                               u16* __restrict__ obf, int M) {
    const int tid = threadIdx.x, lane = tid & 63, w = tid >> 6;
    const int nb = blockIdx.x * 64;
    const int lr = lane & 15, lk = lane >> 4;

    const u16* aRow[4];
#pragma unroll
    for (int m = 0; m < 4; m++) {
        int r = nb + m * 16 + lr;
        if (r >= M) r = M - 1;
        aRow[m] = A + (size_t)r * DD;
    }
    const u16* bb = Bf + (size_t)(w * 2) * 512 + (size_t)lane * 8;

    f32x4 acc[4][2] = {};
#pragma unroll
    for (int kt = 0; kt < 8; ++kt) {
        bf16x8 a[4], b[2];
#pragma unroll
        for (int m = 0; m < 4; m++)
            a[m] = *reinterpret_cast<const bf16x8*>(aRow[m] + kt * 32 + lk * 8);
#pragma unroll
        for (int n = 0; n < 2; n++)
            b[n] = *reinterpret_cast<const bf16x8*>(bb + (size_t)kt * 8192 + n * 512);
#pragma unroll
        for (int m = 0; m < 4; m++)
#pragma unroll
            for (int n = 0; n < 2; n++)
                acc[m][n] = __builtin_amdgcn_mfma_f32_16x16x32_bf16(a[m], b[n], acc[m][n], 0, 0, 0);
    }

#pragma unroll
    for (int n = 0; n < 2; n++) {
        const int col = w * 32 + n * 16 + lr;
        const float bz = bias[col];
#pragma unroll
        for (int m = 0; m < 4; m++) {
            const int r0 = nb + m * 16 + lk * 4;
#pragma unroll
            for (int e = 0; e < 4; e++) {
                const int r = r0 + e;
                if (r < M) obf[(size_t)r * DD + col] = f2bf(fmaxf(acc[m][n][e] + bz, 0.0f));
            }
        }
    }
}

// ---- Fused gather-max + GEMM2, barrier-free interleave ----
// Block = 64 nodes, 8 waves. Wave w: gather nodes w*8..w*8+7 (lane = c7*8+nodeSub,
// lane owns 4x16B chunks of its node's row) interleaved with X-half GEMM
// (direct-global A/B frags). One barrier; agg-half reads LDS fragment tile.
template <bool OUTF32>
__global__ __launch_bounds__(512, 4) void fused_k(const u16* __restrict__ X,
                                                  const u16* __restrict__ h,
                                                  const int* __restrict__ idx,
                                                  const u16* __restrict__ Bf,
                                                  const float* __restrict__ bias,
                                                  u16* __restrict__ obf,
                                                  float* __restrict__ of32, int M) {
    __shared__ int sidx[64 * SS];        // 6.4 KB
    __shared__ u16 aggF[32 * 64 * 8];    // 32 KB: [kc16][row][8 elems]
    const int tid = threadIdx.x, lane = tid & 63, w = tid >> 6;
    const int nb = blockIdx.x * 64;

    for (int j = tid; j < 64 * SS; j += 512) {
        int n = nb + j / SS;
        if (n >= M) n = M - 1;
        sidx[j] = idx[(size_t)n * SS + (j % SS)];
    }
    __syncthreads();

    const int lr = lane & 15, lk = lane >> 4;
    const int nodeSub = lane & 7, c7 = lane >> 3;
    const int myNode = w * 8 + nodeSub;
    const int* myIdx = &sidx[myNode * SS];

    const u16* aRow[4];
#pragma unroll
    for (int m = 0; m < 4; m++) {
        int r = nb + m * 16 + lr;
        if (r >= M) r = M - 1;
        aRow[m] = X + (size_t)r * DD;
    }
    const u16* bb = Bf + (size_t)(w * 2) * 512 + (size_t)lane * 8;

    f32x4 acc[4][2] = {};
    uint4 run[4];
#pragma unroll
    for (int j = 0; j < 4; j++) run[j] = make_uint4(0u, 0u, 0u, 0u);
    uint4 hA[4], hB[4];

#define ISSUE(H, s)                                                           \
    {                                                                         \
        const u16* rp = h + (size_t)myIdx[s] * DD + c7 * 8;                   \
        H[0] = *reinterpret_cast<const uint4*>(rp);                           \
        H[1] = *reinterpret_cast<const uint4*>(rp + 64);                      \
        H[2] = *reinterpret_cast<const uint4*>(rp + 128);                     \
        H[3] = *reinterpret_cast<const uint4*>(rp + 192);                     \
    }
#define CONSUME(H)                                                            \
    {                                                                         \
        run[0] = pkmax4(run[0], H[0]);                                        \
        run[1] = pkmax4(run[1], H[1]);                                        \
        run[2] = pkmax4(run[2], H[2]);                                        \
        run[3] = pkmax4(run[3], H[3]);                                        \
    }

    auto xstep = [&](int kt) {
        bf16x8 a[4], b[2];
#pragma unroll
        for (int m = 0; m < 4; m++)
            a[m] = *reinterpret_cast<const bf16x8*>(aRow[m] + kt * 32 + lk * 8);
#pragma unroll
        for (int n = 0; n < 2; n++)
            b[n] = *reinterpret_cast<const bf16x8*>(bb + (size_t)kt * 8192 + n * 512);
#pragma unroll
        for (int m = 0; m < 4; m++)
#pragma unroll
            for (int n = 0; n < 2; n++)
                acc[m][n] = __builtin_amdgcn_mfma_f32_16x16x32_bf16(a[m], b[n], acc[m][n], 0, 0, 0);
    };

    ISSUE(hA, 0);
    ISSUE(hB, 1);
#pragma unroll
    for (int s = 2; s < 27; ++s) {
        if (s % 3 == 2 && s < 26) xstep(s / 3);  // kt = 0..7 at s = 2,5,...,23
        if (s & 1) {
            CONSUME(hB);
            if (s < 25) ISSUE(hB, s);
        } else {
            CONSUME(hA);
            if (s < 25) ISSUE(hA, s);
        }
    }

    // write gather result: lane owns kc16 = c7+8j, row = myNode
#pragma unroll
    for (int j = 0; j < 4; j++)
        *reinterpret_cast<uint4*>(&aggF[((size_t)(c7 + 8 * j) * 64 + myNode) * 8]) = run[j];
    __syncthreads();

    // agg-half: K = 256 from LDS fragment tile, B frags kt = 8..15
#pragma unroll
    for (int kt8 = 0; kt8 < 8; ++kt8) {
        bf16x8 a[4], b[2];
#pragma unroll
        for (int m = 0; m < 4; m++)
            a[m] = *reinterpret_cast<const bf16x8*>(
                &aggF[((size_t)(kt8 * 4 + lk) * 64 + m * 16 + lr) * 8]);
#pragma unroll
        for (int n = 0; n < 2; n++)
            b[n] = *reinterpret_cast<const bf16x8*>(bb + (size_t)(8 + kt8) * 8192 + n * 512);
#pragma unroll
        for (int m = 0; m < 4; m++)
#pragma unroll
            for (int n = 0; n < 2; n++)
                acc[m][n] = __builtin_amdgcn_mfma_f32_16x16x32_bf16(a[m], b[n], acc[m][n], 0, 0, 0);
    }

#pragma unroll
    for (int n = 0; n < 2; n++) {
        const int col = w * 32 + n * 16 + lr;
        const float bz = bias[col];
#pragma unroll
        for (int m = 0; m < 4; m++) {
            const int r0 = nb + m * 16 + lk * 4;
#pragma unroll
            for (int e = 0; e < 4; e++) {
                const int r = r0 + e;
                if (r < M) {
                    float v = acc[m][n][e] + bz;
                    if (OUTF32)
                        of32[(size_t)r * DD + col] = v;
                    else
                        obf[(size_t)r * DD + col] = f2bf(fmaxf(v, 0.0f));  // inter-layer relu
                }
            }
        }
    }
#undef ISSUE
#undef CONSUME
}

extern "C" void kernel_launch(void* const* d_in, const int* in_sizes, int n_in,
                              void* d_out, int out_size, void* d_ws, size_t ws_size,
                              hipStream_t stream) {
    const float* features = (const float*)d_in[0];
    const int* neigh = (const int*)d_in[1];
    const float* Wp0 = (const float*)d_in[2];
    const float* bp0 = (const float*)d_in[3];
    const float* Wfc0 = (const float*)d_in[4];
    const float* bfc0 = (const float*)d_in[5];
    const float* Wp1 = (const float*)d_in[6];
    const float* bp1 = (const float*)d_in[7];
    const float* Wfc1 = (const float*)d_in[8];
    const float* bfc1 = (const float*)d_in[9];
    float* out = (float*)d_out;

    const size_t ND = (size_t)N_NODES * DD;  // 12.8M
    u16* B0 = (u16*)d_ws;      // X bf16 -> later h1
    u16* B1 = B0 + ND;         // h0
    u16* B2 = B1 + ND;         // O0 (layer-0 output)
    u16* Wpb0 = B2 + ND;
    u16* Wfb0 = Wpb0 + 65536;
    u16* Wpb1 = Wfb0 + 131072;
    u16* Wfb1 = Wpb1 + 65536;

    cvt_w_k<<<32, 256, 0, stream>>>(Wp0, Wpb0, 8);
    cvt_w_k<<<64, 256, 0, stream>>>(Wfc0, Wfb0, 16);
    cvt_w_k<<<32, 256, 0, stream>>>(Wp1, Wpb1, 8);
    cvt_w_k<<<64, 256, 0, stream>>>(Wfc1, Wfb1, 16);
    cvt_f32_bf16_k<<<12500, 256, 0, stream>>>((const float4*)features, B0);

    const int gb = (N_NODES + 63) / 64;  // 782

    // ---- layer 0 ----
    gemm1_k<<<gb, 512, 0, stream>>>(B0, Wpb0, bp0, B1, N_NODES);
    fused_k<false><<<gb, 512, 0, stream>>>(B0, B1, neigh, Wfb0, bfc0, B2, nullptr, N_NODES);

    // ---- layer 1 ---- (B0 dead -> h1)
    gemm1_k<<<gb, 512, 0, stream>>>(B2, Wpb1, bp1, B0, N_NODES);
    fused_k<true><<<gb, 512, 0, stream>>>(B2, B0, neigh, Wfb1, bfc1, nullptr, out, N_NODES);
}

// Round 6
// 281.173 us; speedup vs baseline: 1.3787x; 1.3787x over previous
//
#include <hip/hip_runtime.h>
#include <stdint.h>

#define N_NODES 50000
#define DD 256
#define SS 25

typedef unsigned short u16;
typedef __attribute__((ext_vector_type(8))) __bf16 bf16x8;
typedef __attribute__((ext_vector_type(4))) float f32x4;

__device__ __forceinline__ u16 f2bf(float f) {  // round-to-nearest-even
    union { float f; uint32_t i; } c;
    c.f = f;
    uint32_t r = c.i + 0x7fffu + ((c.i >> 16) & 1u);
    return (u16)(r >> 16);
}

// packed max of 2 non-negative bf16 (bit patterns monotone, sign bit 0 -> signed i16 max is exact)
__device__ __forceinline__ uint4 pkmax4(uint4 a, uint4 b) {
    uint4 d;
    asm("v_pk_max_i16 %0, %1, %2" : "=v"(d.x) : "v"(a.x), "v"(b.x));
    asm("v_pk_max_i16 %0, %1, %2" : "=v"(d.y) : "v"(a.y), "v"(b.y));
    asm("v_pk_max_i16 %0, %1, %2" : "=v"(d.z) : "v"(a.z), "v"(b.z));
    asm("v_pk_max_i16 %0, %1, %2" : "=v"(d.w) : "v"(a.w), "v"(b.w));
    return d;
}

__device__ __forceinline__ void gld16(void* lds, const void* g) {
    __builtin_amdgcn_global_load_lds(
        (const __attribute__((address_space(1))) uint32_t*)g,
        (__attribute__((address_space(3))) uint32_t*)lds, 16, 0, 0);
}

// ---- f32 -> bf16 elementwise (exact: grid*block*4 == n) ----
__global__ __launch_bounds__(256) void cvt_f32_bf16_k(const float4* __restrict__ in,
                                                      u16* __restrict__ out) {
    int i = blockIdx.x * 256 + threadIdx.x;
    float4 v = in[i];
    uint2 o;
    o.x = (uint32_t)f2bf(v.x) | ((uint32_t)f2bf(v.y) << 16);
    o.y = (uint32_t)f2bf(v.z) | ((uint32_t)f2bf(v.w) << 16);
    *reinterpret_cast<uint2*>(out + (size_t)i * 4) = o;
}

// ---- weight f32 [K][256] -> bf16 MFMA B-fragment layout ----
// out[((kt*16 + ct)*64 + lane)*8 + e] = W[kt*32 + (lane>>4)*8 + e][ct*16 + (lane&15)]
__global__ __launch_bounds__(256) void cvt_w_k(const float* __restrict__ W,
                                               u16* __restrict__ out, int KT) {
    int t = blockIdx.x * 256 + threadIdx.x;
    if (t >= KT * 16 * 64) return;
    int lane = t & 63;
    int ct = (t >> 6) & 15;
    int kt = t >> 10;
    int k0 = kt * 32 + (lane >> 4) * 8;
    int col = ct * 16 + (lane & 15);
    u16 r[8];
#pragma unroll
    for (int e = 0; e < 8; e++) r[e] = f2bf(W[(size_t)(k0 + e) * DD + col]);
    uint4 v;
    v.x = (uint32_t)r[0] | ((uint32_t)r[1] << 16);
    v.y = (uint32_t)r[2] | ((uint32_t)r[3] << 16);
    v.z = (uint32_t)r[4] | ((uint32_t)r[5] << 16);
    v.w = (uint32_t)r[6] | ((uint32_t)r[7] << 16);
    *reinterpret_cast<uint4*>(out + (size_t)t * 8) = v;
}

// ---- XCD-sliced gather + max-pool ----
// h chunked [8][N][32] bf16. Block handles chunk c = bid&7, node group g = bid>>3.
// Round-robin bid->XCD => XCD x only touches slice x (3.2MB, L2-resident).
// 4 lanes per node (16B each of the 64B chunk), 25 pipelined L2-hit loads.
__global__ __launch_bounds__(256) void gather_xcd_k(const u16* __restrict__ hc,
                                                    const int* __restrict__ idx,
                                                    u16* __restrict__ agg, int M) {
    const int c = blockIdx.x & 7;
    const int base = (blockIdx.x >> 3) * 64;
    __shared__ int soff[64 * SS];  // element offsets into slice: idx*32
    const int tid = threadIdx.x;
    for (int j = tid; j < 64 * SS; j += 256) {
        int n = base + j / SS;
        if (n >= M) n = M - 1;
        soff[j] = idx[(size_t)n * SS + (j % SS)] * 32;
    }
    __syncthreads();
    const int grp = tid >> 2;  // node slot 0..63
    const int q = tid & 3;     // which 16B quarter of the 64B chunk
    const int n = base + grp;
    const u16* slice = hc + (size_t)c * ((size_t)N_NODES * 32) + q * 8;
    const int* off = &soff[grp * SS];
    uint4 run = make_uint4(0u, 0u, 0u, 0u);
#pragma unroll
    for (int s = 0; s < SS; ++s) {
        uint4 v = *reinterpret_cast<const uint4*>(slice + off[s]);
        run = pkmax4(run, v);
    }
    if (n < M)
        *reinterpret_cast<uint4*>(agg + (size_t)n * DD + c * 32 + q * 8) = run;
}

// ---- bf16 MFMA GEMM: out[M,256] = [A1 | A2][M, 32*KT] @ Bf + bias ----
// 128x128 tile, 4 waves (2x2), double-buffered LDS, global_load_lds width 16.
// OMODE: 0 = bf16 row-major [N][256], 1 = bf16 chunked [8][N][32], 2 = f32 row-major.
template <int KT, bool RELU, int OMODE>
__global__ __launch_bounds__(256) void gemm_k(const u16* __restrict__ A1,
                                              const u16* __restrict__ A2,
                                              const u16* __restrict__ Bf,
                                              const float* __restrict__ bias,
                                              u16* __restrict__ obf,
                                              float* __restrict__ of32, int M) {
    __shared__ u16 sAB[2][8192];  // per buf: A [0,4096), B [4096,8192)
    const int lane = threadIdx.x & 63;
    const int w = threadIdx.x >> 6;
    const int wm = w >> 1, wn = w & 1;
    const int row_base = blockIdx.x * 128;
    const int ct0b = blockIdx.y * 8;
    const int lr = lane & 15, lk = lane >> 4;

    f32x4 acc[4][4] = {};

    auto stage = [&](int buf, int kt) {
        const u16* Ab = (KT == 16 && kt >= 8) ? A2 : A1;
        const int kk = kt & 7;
#pragma unroll
        for (int j = 0; j < 2; ++j) {
            int row = row_base + j * 64 + lane;
            if (row >= M) row = M - 1;
            gld16(&sAB[buf][(w * 2 + j) * 512 + lane * 8],
                  Ab + (size_t)row * DD + kk * 32 + w * 8);
        }
#pragma unroll
        for (int j = 0; j < 2; ++j) {
            const int nl = w * 2 + j;
            gld16(&sAB[buf][4096 + nl * 512 + lane * 8],
                  Bf + ((size_t)(kt * 16 + ct0b + nl) * 64 + lane) * 8);
        }
    };

    auto compute = [&](int buf) {
        bf16x8 a[4], b[4];
#pragma unroll
        for (int m = 0; m < 4; m++)
            a[m] = *reinterpret_cast<const bf16x8*>(
                &sAB[buf][lk * 1024 + (wm * 64 + m * 16 + lr) * 8]);
#pragma unroll
        for (int n = 0; n < 4; n++)
            b[n] = *reinterpret_cast<const bf16x8*>(
                &sAB[buf][4096 + (wn * 4 + n) * 512 + lane * 8]);
#pragma unroll
        for (int m = 0; m < 4; m++)
#pragma unroll
            for (int n = 0; n < 4; n++)
                acc[m][n] = __builtin_amdgcn_mfma_f32_16x16x32_bf16(a[m], b[n], acc[m][n], 0, 0, 0);
    };

    stage(0, 0);
    asm volatile("s_waitcnt vmcnt(0)" ::: "memory");
    __syncthreads();
    int buf = 0;
#pragma unroll
    for (int kt = 0; kt < KT - 1; ++kt) {
        stage(buf ^ 1, kt + 1);
        compute(buf);
        asm volatile("s_waitcnt vmcnt(0)" ::: "memory");
        __syncthreads();
        buf ^= 1;
    }
    compute(buf);

    const int col_base = blockIdx.y * 128 + wn * 64;
#pragma unroll
    for (int n = 0; n < 4; n++) {
        const int col = col_base + n * 16 + lr;
        const float bz = bias[col];
#pragma unroll
        for (int m = 0; m < 4; m++) {
            const int r0 = row_base + wm * 64 + m * 16 + lk * 4;
#pragma unroll
            for (int e = 0; e < 4; e++) {
                const int r = r0 + e;
                if (r < M) {
                    float v = acc[m][n][e] + bz;
                    if (RELU) v = fmaxf(v, 0.0f);
                    if (OMODE == 0)
                        obf[(size_t)r * DD + col] = f2bf(v);
                    else if (OMODE == 1)  // chunked h: [col>>5][r][col&31]
                        obf[((size_t)(col >> 5) * N_NODES + r) * 32 + (col & 31)] = f2bf(v);
                    else
                        of32[(size_t)r * DD + col] = v;
                }
            }
        }
    }
}

extern "C" void kernel_launch(void* const* d_in, const int* in_sizes, int n_in,
                              void* d_out, int out_size, void* d_ws, size_t ws_size,
                              hipStream_t stream) {
    const float* features = (const float*)d_in[0];
    const int* neigh = (const int*)d_in[1];
    const float* Wp0 = (const float*)d_in[2];
    const float* bp0 = (const float*)d_in[3];
    const float* Wfc0 = (const float*)d_in[4];
    const float* bfc0 = (const float*)d_in[5];
    const float* Wp1 = (const float*)d_in[6];
    const float* bp1 = (const float*)d_in[7];
    const float* Wfc1 = (const float*)d_in[8];
    const float* bfc1 = (const float*)d_in[9];
    float* out = (float*)d_out;

    const size_t ND = (size_t)N_NODES * DD;  // 12.8M
    u16* B0 = (u16*)d_ws;      // X bf16 -> later h1 (chunked)
    u16* B1 = B0 + ND;         // h0 (chunked) -> later O0 (row-major)
    u16* B2 = B1 + ND;         // agg (row-major)
    u16* Wpb0 = B2 + ND;
    u16* Wfb0 = Wpb0 + 65536;
    u16* Wpb1 = Wfb0 + 131072;
    u16* Wfb1 = Wpb1 + 65536;

    cvt_w_k<<<32, 256, 0, stream>>>(Wp0, Wpb0, 8);
    cvt_w_k<<<64, 256, 0, stream>>>(Wfc0, Wfb0, 16);
    cvt_w_k<<<32, 256, 0, stream>>>(Wp1, Wpb1, 8);
    cvt_w_k<<<64, 256, 0, stream>>>(Wfc1, Wfb1, 16);
    cvt_f32_bf16_k<<<12500, 256, 0, stream>>>((const float4*)features, B0);

    dim3 gg((N_NODES + 127) / 128, 2);
    const int gb = (N_NODES + 63) / 64;  // 782
    const int gxcd = gb * 8;             // 6256: chunk = bid&7 -> per-XCD slice

    // ---- layer 0 ----
    gemm_k<8, true, 1><<<gg, 256, 0, stream>>>(B0, nullptr, Wpb0, bp0, B1, nullptr, N_NODES);
    gather_xcd_k<<<gxcd, 256, 0, stream>>>(B1, neigh, B2, N_NODES);
    gemm_k<16, true, 0><<<gg, 256, 0, stream>>>(B0, B2, Wfb0, bfc0, B1, nullptr, N_NODES);

    // ---- layer 1 ---- (B0 dead -> h1 chunked; B1 holds O0)
    gemm_k<8, true, 1><<<gg, 256, 0, stream>>>(B1, nullptr, Wpb1, bp1, B0, nullptr, N_NODES);
    gather_xcd_k<<<gxcd, 256, 0, stream>>>(B0, neigh, B2, N_NODES);
    gemm_k<16, false, 2><<<gg, 256, 0, stream>>>(B1, B2, Wfb1, bfc1, nullptr, out, N_NODES);
}